// Round 4
// baseline (3402.147 us; speedup 1.0000x reference)
//
#include <hip/hip_runtime.h>
#include <cstdint>

#define D_MODEL 1024
#define NHEAD   16
#define NLAYER  6
#define DIM_FF  4096
#define SEQ_B   8
#define SEQ_L   1024
#define TOKENS  (SEQ_B*SEQ_L)   // 8192

typedef __bf16 v8bf  __attribute__((ext_vector_type(8)));
typedef __bf16 v4bf  __attribute__((ext_vector_type(4)));
typedef float  v4f   __attribute__((ext_vector_type(4)));

__device__ __forceinline__ void gl_lds16(const void* g, void* l) {
  __builtin_amdgcn_global_load_lds(
      (const __attribute__((address_space(1))) void*)g,
      (__attribute__((address_space(3))) void*)l, 16, 0, 0);
}

// ---------------- weight fp32 -> bf16 (vectorized) ----------------
__global__ __launch_bounds__(256) void f2b_kernel(const float4* __restrict__ in,
                                                  ushort4* __restrict__ out, long n4) {
  long i = (long)blockIdx.x * 256 + threadIdx.x;
  long stride = (long)gridDim.x * 256;
  for (; i < n4; i += stride) {
    float4 v = in[i];
    v4bf r = { (__bf16)v.x, (__bf16)v.y, (__bf16)v.z, (__bf16)v.w };
    out[i] = *(ushort4*)&r;
  }
}

// ---------------- embedding (vectorized) ----------------
__global__ __launch_bounds__(256) void embed_kernel(const int* __restrict__ ids,
    const float4* __restrict__ tok, const float4* __restrict__ pos,
    float4* __restrict__ X, ushort4* __restrict__ Xb) {
  long i = (long)blockIdx.x * 256 + threadIdx.x;   // over TOKENS*256
  int d4 = (int)(i & 255);
  long bl = i >> 8;
  int l = (int)(bl & (SEQ_L - 1));
  int id = ids[bl];
  float4 t = tok[(long)id * 256 + d4];
  float4 p = pos[(long)l * 256 + d4];
  float4 v = {t.x + p.x, t.y + p.y, t.z + p.z, t.w + p.w};
  X[i] = v;
  v4bf r = { (__bf16)v.x, (__bf16)v.y, (__bf16)v.z, (__bf16)v.w };
  Xb[i] = *(ushort4*)&r;
}

// ---------------- additive mask bias ----------------
__global__ __launch_bounds__(256) void maskb_kernel(const int* __restrict__ ids,
                                                    float* __restrict__ mb) {
  int i = blockIdx.x * 256 + threadIdx.x;   // 0..8191
  mb[i] = (ids[i] == 0 && (i & 1023) != 0) ? -1e9f : 0.f;
}

// ---------------- 128x128 GEMM: C[M,N] = A[M,K] @ W[N,K]^T + bias (+Res) --------
// Double-buffered LDS, ONE barrier per K-step (prefetch k+1 while computing k).
// EPI: 0 = fp32 (+Res residual) -> Cf; 1 = gelu(tanh) -> bf16 Cb;
//      3 = QKV: cols<2048 bf16 -> Cb, cols>=2048 (V) transposed -> Vt
template<int EPI>
__global__ __launch_bounds__(256) void gemm128(
    const unsigned short* __restrict__ A,
    const unsigned short* __restrict__ W,
    const float* __restrict__ bias,
    const float* __restrict__ Res,
    float* __restrict__ Cf, unsigned short* __restrict__ Cb,
    unsigned short* __restrict__ Vt,
    int M, int N, int K) {
  __shared__ unsigned short As[2 * 128 * 32];   // 16 KB
  __shared__ unsigned short Bs[2 * 128 * 32];   // 16 KB
  int tid = threadIdx.x;
  int wave = tid >> 6, lane = tid & 63;
  int l15 = lane & 15, quad = lane >> 4;

  // XCD-contiguous supertile: 8 M-tiles per XCD, N slow
  int id = blockIdx.y * gridDim.x + blockIdx.x;
  int xcd = id & 7, sidx = id >> 3;
  int mt = xcd * 8 + (sidx & 7);
  int nt = sidx >> 3;
  int m0 = mt * 128, n0 = nt * 128;
  int wm = (wave >> 1) * 64, wn = (wave & 1) * 64;

  // staging: thread t -> LDS unit t (row t>>2, phys slot t&3); global slot XOR-swizzled
  int srow = tid >> 2;
  int ssl  = (tid & 3) ^ ((srow >> 1) & 3);
  int sc8  = ssl << 3;
  const unsigned short* Ag0 = A + (long)(m0 + srow) * K + sc8;
  const unsigned short* Ag1 = A + (long)(m0 + srow + 64) * K + sc8;
  const unsigned short* Wg0 = W + (long)(n0 + srow) * K + sc8;
  const unsigned short* Wg1 = W + (long)(n0 + srow + 64) * K + sc8;
  unsigned short* As0 = As + tid * 8;
  unsigned short* Bs0 = Bs + tid * 8;

  // fragment read pointers (buffer 0; buffer 1 = +4096 elem immediate offset)
  const unsigned short* afp[4];
  const unsigned short* bfp[4];
  #pragma unroll
  for (int i = 0; i < 4; ++i) {
    int r = wm + i * 16 + l15;
    afp[i] = &As[r * 32 + ((quad ^ ((r >> 1) & 3)) << 3)];
    int rb = wn + i * 16 + l15;
    bfp[i] = &Bs[rb * 32 + ((quad ^ ((rb >> 1) & 3)) << 3)];
  }

  v4f acc[4][4];
  #pragma unroll
  for (int i = 0; i < 4; ++i)
    #pragma unroll
    for (int j = 0; j < 4; ++j) acc[i][j] = (v4f){0.f, 0.f, 0.f, 0.f};

  auto compute = [&](int bo) {   // bo: element offset of buffer (0 or 4096)
    v8bf af[4], bb[4];
    #pragma unroll
    for (int i = 0; i < 4; ++i) af[i] = *(const v8bf*)(afp[i] + bo);
    #pragma unroll
    for (int j = 0; j < 4; ++j) bb[j] = *(const v8bf*)(bfp[j] + bo);
    #pragma unroll
    for (int i = 0; i < 4; ++i)
      #pragma unroll
      for (int j = 0; j < 4; ++j)
        acc[i][j] = __builtin_amdgcn_mfma_f32_16x16x32_bf16(af[i], bb[j], acc[i][j], 0, 0, 0);
  };

  // prologue: stage k-step 0 into buffer 0
  gl_lds16(Ag0, As0);
  gl_lds16(Ag1, As0 + 2048);
  gl_lds16(Wg0, Bs0);
  gl_lds16(Wg1, Bs0 + 2048);

  int ksteps = K >> 5;    // always even
  for (int ks = 0; ks < ksteps; ks += 2) {
    // step A: compute buf0 (k=ks), prefetch k=ks+1 into buf1 (always exists)
    __syncthreads();                     // drains buf0's staging loads
    {
      int k1 = (ks + 1) << 5;
      gl_lds16(Ag0 + k1, As0 + 4096);
      gl_lds16(Ag1 + k1, As0 + 6144);
      gl_lds16(Wg0 + k1, Bs0 + 4096);
      gl_lds16(Wg1 + k1, Bs0 + 6144);
    }
    compute(0);
    // step B: compute buf1 (k=ks+1), prefetch k=ks+2 into buf0
    __syncthreads();                     // drains buf1's staging loads
    if (ks + 2 < ksteps) {
      int k2 = (ks + 2) << 5;
      gl_lds16(Ag0 + k2, As0);
      gl_lds16(Ag1 + k2, As0 + 2048);
      gl_lds16(Wg0 + k2, Bs0);
      gl_lds16(Wg1 + k2, Bs0 + 2048);
    }
    compute(4096);
  }

  #pragma unroll
  for (int i = 0; i < 4; ++i) {
    int crow0 = m0 + wm + i * 16 + quad * 4;
    #pragma unroll
    for (int j = 0; j < 4; ++j) {
      int col = n0 + wn + j * 16 + l15;
      float bv = bias[col];
      if (EPI == 3 && col >= 2048) {
        int hc = (col - 2048) >> 6, d = (col - 2048) & 63;
        int bb2 = crow0 >> 10, l = crow0 & 1023;
        v4bf pk = { (__bf16)(acc[i][j][0] + bv), (__bf16)(acc[i][j][1] + bv),
                    (__bf16)(acc[i][j][2] + bv), (__bf16)(acc[i][j][3] + bv) };
        *(ushort4*)&Vt[((long)((bb2 * 16 + hc) * 64 + d)) * 1024 + l] = *(ushort4*)&pk;
      } else {
        #pragma unroll
        for (int r = 0; r < 4; ++r) {
          float v = acc[i][j][r] + bv;
          long idx = (long)(crow0 + r) * N + col;
          if (EPI == 1) {
            // tanh-form GELU (err <= ~1e-3, far below bf16 quantization)
            float u = v * (0.7978845608028654f + 0.03567740814f * v * v);
            float e = __builtin_amdgcn_exp2f(u * 2.885390081777927f);  // exp(2u)
            float th = 1.f - 2.f / (e + 1.f);
            v = 0.5f * v * (1.f + th);
          }
          if (EPI == 0) Cf[idx] = v + Res[idx];
          else          ((__bf16*)Cb)[idx] = (__bf16)v;
        }
      }
    }
  }
}

// ---------------- MFMA flash attention ----------------
// grid (L/128, NHEAD, B), block 256. 2 Q-tiles per wave (128 q/block).
// Double-buffered K/V staging, one barrier per 64-key chunk.
#define PSP 72
__global__ __launch_bounds__(256) void attn2(
    const unsigned short* __restrict__ QKVb,
    const unsigned short* __restrict__ Vtg,
    const float* __restrict__ mb,
    unsigned short* __restrict__ Ob) {
  __shared__ unsigned short Ks[2 * 64 * 64];   // [buf][key][d] swizzled, 16 KB
  __shared__ unsigned short Vs[2 * 64 * 64];   // [buf][d][key] swizzled, 16 KB
  __shared__ unsigned short Ps[4][16 * PSP];   // per-wave P round-trip
  int tid = threadIdx.x, wave = tid >> 6, lane = tid & 63;
  int l15 = lane & 15, quad = lane >> 4;
  int b = blockIdx.z, h = blockIdx.y, q0 = blockIdx.x * 128;

  // Q fragments for both tiles
  v8bf gq[2][2];
  #pragma unroll
  for (int t = 0; t < 2; ++t) {
    int qrow = q0 + t * 64 + wave * 16 + l15;
    const unsigned short* qb = QKVb + (long)(b * 1024 + qrow) * 3072 + h * 64;
    gq[t][0] = *(const v8bf*)(qb + quad * 8);
    gq[t][1] = *(const v8bf*)(qb + 32 + quad * 8);
  }

  v8bf bones;   // ones in col 0 -> row-sum MFMA
  #pragma unroll
  for (int j = 0; j < 8; ++j) bones[j] = (l15 == 0) ? (__bf16)1.0f : (__bf16)0.0f;

  float m_run[2][4], l_run[2][4];
  v4f O[2][4];
  #pragma unroll
  for (int t = 0; t < 2; ++t)
    #pragma unroll
    for (int r = 0; r < 4; ++r) {
      m_run[t][r] = -1e30f; l_run[t][r] = 0.f;
      O[t][r] = (v4f){0.f, 0.f, 0.f, 0.f};
    }

  const unsigned short* kgb = QKVb + (long)b * 1024 * 3072 + 1024 + h * 64;
  const unsigned short* vgb = Vtg + (long)((b * 16 + h) * 64) * 1024;
  const float* mrow = mb + b * 1024;

  int srow = tid >> 3;                  // 0..31
  int ssl  = (tid & 7) ^ (srow & 7);    // swizzled global slot
  int ph0 = (quad ^ (l15 & 7)) << 3;
  int ph1 = ((quad + 4) ^ (l15 & 7)) << 3;
  const float SC = 0.18033688011112042f;   // 0.125 * log2(e)

  // prologue: chunk 0 -> buf 0
  gl_lds16(kgb + (long)srow * 3072 + ssl * 8, &Ks[tid * 8]);
  gl_lds16(kgb + (long)(srow + 32) * 3072 + ssl * 8, &Ks[tid * 8 + 2048]);
  gl_lds16(vgb + (long)srow * 1024 + ssl * 8, &Vs[tid * 8]);
  gl_lds16(vgb + (long)(srow + 32) * 1024 + ssl * 8, &Vs[tid * 8 + 2048]);

  for (int c = 0; c < 16; ++c) {
    int cbo = (c & 1) * 4096;            // current buffer elem offset
    __syncthreads();                     // drains current buffer's staging
    if (c + 1 < 16) {
      int nbo = 4096 - cbo;
      int k0n = (c + 1) * 64;
      gl_lds16(kgb + (long)(k0n + srow) * 3072 + ssl * 8, &Ks[nbo + tid * 8]);
      gl_lds16(kgb + (long)(k0n + srow + 32) * 3072 + ssl * 8, &Ks[nbo + tid * 8 + 2048]);
      gl_lds16(vgb + (long)srow * 1024 + k0n + ssl * 8, &Vs[nbo + tid * 8]);
      gl_lds16(vgb + (long)(srow + 32) * 1024 + k0n + ssl * 8, &Vs[nbo + tid * 8 + 2048]);
    }
    int k0 = c * 64;

    // K fragments once, reused by both Q-tiles
    v8bf kf0[4], kf1[4];
    #pragma unroll
    for (int t = 0; t < 4; ++t) {
      kf0[t] = *(const v8bf*)&Ks[cbo + (t * 16 + l15) * 64 + ph0];
      kf1[t] = *(const v8bf*)&Ks[cbo + (t * 16 + l15) * 64 + ph1];
    }
    float mbv[4];
    #pragma unroll
    for (int t = 0; t < 4; ++t) mbv[t] = mrow[k0 + t * 16 + l15];

    #pragma unroll
    for (int tt = 0; tt < 2; ++tt) {
      float p[4][4], mr[4];
      #pragma unroll
      for (int r = 0; r < 4; ++r) mr[r] = -1e30f;
      #pragma unroll
      for (int t = 0; t < 4; ++t) {
        v4f s = (v4f){0.f, 0.f, 0.f, 0.f};
        s = __builtin_amdgcn_mfma_f32_16x16x32_bf16(gq[tt][0], kf0[t], s, 0, 0, 0);
        s = __builtin_amdgcn_mfma_f32_16x16x32_bf16(gq[tt][1], kf1[t], s, 0, 0, 0);
        #pragma unroll
        for (int r = 0; r < 4; ++r) {
          float sv = fmaf(s[r], SC, mbv[t]);
          p[t][r] = sv;
          mr[r] = fmaxf(mr[r], sv);
        }
      }
      #pragma unroll
      for (int r = 0; r < 4; ++r) {
        mr[r] = fmaxf(mr[r], __shfl_xor(mr[r], 1, 64));
        mr[r] = fmaxf(mr[r], __shfl_xor(mr[r], 2, 64));
        mr[r] = fmaxf(mr[r], __shfl_xor(mr[r], 4, 64));
        mr[r] = fmaxf(mr[r], __shfl_xor(mr[r], 8, 64));
      }
      float alpha[4];
      #pragma unroll
      for (int r = 0; r < 4; ++r) {
        float mn = fmaxf(m_run[tt][r], mr[r]);
        alpha[r] = __builtin_amdgcn_exp2f(m_run[tt][r] - mn);
        m_run[tt][r] = mn;
      }
      #pragma unroll
      for (int t = 0; t < 4; ++t)
        #pragma unroll
        for (int r = 0; r < 4; ++r)
          p[t][r] = __builtin_amdgcn_exp2f(p[t][r] - m_run[tt][r]);

      // P: C-layout -> LDS -> A-layout (wave-private, in-order DS ops)
      #pragma unroll
      for (int t = 0; t < 4; ++t)
        #pragma unroll
        for (int r = 0; r < 4; ++r)
          ((__bf16*)Ps[wave])[(quad * 4 + r) * PSP + t * 16 + l15] = (__bf16)p[t][r];
      v8bf pa0 = *(const v8bf*)&Ps[wave][l15 * PSP + quad * 8];
      v8bf pa1 = *(const v8bf*)&Ps[wave][l15 * PSP + 32 + quad * 8];

      v4f ss = (v4f){0.f, 0.f, 0.f, 0.f};
      ss = __builtin_amdgcn_mfma_f32_16x16x32_bf16(pa0, bones, ss, 0, 0, 0);
      ss = __builtin_amdgcn_mfma_f32_16x16x32_bf16(pa1, bones, ss, 0, 0, 0);

      #pragma unroll
      for (int j = 0; j < 4; ++j)
        #pragma unroll
        for (int r = 0; r < 4; ++r) O[tt][j >= 0 ? j : j][r] *= (j == 0 ? alpha[r] : 1.f);
      // (scale all j: do it explicitly)
      #pragma unroll
      for (int j = 1; j < 4; ++j)
        #pragma unroll
        for (int r = 0; r < 4; ++r) O[tt][j][r] *= alpha[r];

      #pragma unroll
      for (int j = 0; j < 4; ++j) {
        v8bf vf0 = *(const v8bf*)&Vs[cbo + (j * 16 + l15) * 64 + ph0];
        v8bf vf1 = *(const v8bf*)&Vs[cbo + (j * 16 + l15) * 64 + ph1];
        O[tt][j] = __builtin_amdgcn_mfma_f32_16x16x32_bf16(pa0, vf0, O[tt][j], 0, 0, 0);
        O[tt][j] = __builtin_amdgcn_mfma_f32_16x16x32_bf16(pa1, vf1, O[tt][j], 0, 0, 0);
      }
      #pragma unroll
      for (int r = 0; r < 4; ++r)
        l_run[tt][r] = l_run[tt][r] * alpha[r] + __shfl(ss[r], quad << 4, 64);
    }
  }

  #pragma unroll
  for (int tt = 0; tt < 2; ++tt) {
    int qd = q0 + tt * 64 + wave * 16 + quad * 4;
    #pragma unroll
    for (int r = 0; r < 4; ++r) {
      float inv = 1.f / l_run[tt][r];
      #pragma unroll
      for (int j = 0; j < 4; ++j)
        ((__bf16*)Ob)[(long)(b * 1024 + qd + r) * 1024 + h * 64 + j * 16 + l15] =
            (__bf16)(O[tt][j][r] * inv);
    }
  }
}

// ---------------- residual(optional) + LayerNorm (fp32), writes fp32 + bf16 ------
__global__ __launch_bounds__(256) void add_ln(
    const float* __restrict__ Xin, const float* __restrict__ Yin,
    const float* __restrict__ g, const float* __restrict__ bta,
    float* __restrict__ outF, unsigned short* __restrict__ outB,
    long in_stride, long out_stride) {
  int row = blockIdx.x;
  const float* x = Xin + (long)row * in_stride;
  const float* y = Yin ? Yin + (long)row * 1024 : nullptr;
  int tid = threadIdx.x;
  float v[4];
  float s = 0.f, s2 = 0.f;
  #pragma unroll
  for (int j = 0; j < 4; ++j) {
    int d = j * 256 + tid;
    float t = x[d] + (y ? y[d] : 0.f);
    v[j] = t; s += t; s2 += t * t;
  }
  __shared__ float red[8];
  int lane = tid & 63, wave = tid >> 6;
  #pragma unroll
  for (int o = 32; o > 0; o >>= 1) { s += __shfl_down(s, o, 64); s2 += __shfl_down(s2, o, 64); }
  if (lane == 0) { red[wave] = s; red[4 + wave] = s2; }
  __syncthreads();
  s  = red[0] + red[1] + red[2] + red[3];
  s2 = red[4] + red[5] + red[6] + red[7];
  float mean = s * (1.f / 1024.f);
  float var  = s2 * (1.f / 1024.f) - mean * mean;
  float rstd = rsqrtf(var + 1e-5f);
  float* of = outF + (long)row * out_stride;
  unsigned short* ob = outB ? outB + (long)row * out_stride : nullptr;
  #pragma unroll
  for (int j = 0; j < 4; ++j) {
    int d = j * 256 + tid;
    float o = (v[j] - mean) * rstd * g[d] + bta[d];
    of[d] = o;
    if (ob) ((__bf16*)ob)[d] = (__bf16)o;
  }
}

// ---------------- head ----------------
__global__ __launch_bounds__(256) void head_kernel(
    const float* __restrict__ cls, const float* __restrict__ hW,
    const float* __restrict__ hb, float* __restrict__ out) {
  int n = blockIdx.x * 256 + threadIdx.x;
  int b = blockIdx.y;
  const float4* c4 = (const float4*)(cls + b * 1024);
  const float4* w4 = (const float4*)(hW + (long)n * 1024);
  float s = 0.f;
  #pragma unroll 8
  for (int d = 0; d < 256; ++d) {
    float4 a = c4[d], w = w4[d];
    s += a.x * w.x + a.y * w.y + a.z * w.z + a.w * w.w;
  }
  out[b * 1024 + n] = s + hb[n];
}

extern "C" void kernel_launch(void* const* d_in, const int* in_sizes, int n_in,
                              void* d_out, int out_size, void* d_ws, size_t ws_size,
                              hipStream_t stream) {
  const int*   ids  = (const int*)d_in[0];
  const float* tok  = (const float*)d_in[1];
  const float* pos  = (const float*)d_in[2];
  const float* Wqkv = (const float*)d_in[3];
  const float* bqkv = (const float*)d_in[4];
  const float* Wo   = (const float*)d_in[5];
  const float* bo   = (const float*)d_in[6];
  const float* ln1g = (const float*)d_in[7];
  const float* ln1b = (const float*)d_in[8];
  const float* W1   = (const float*)d_in[9];
  const float* b1   = (const float*)d_in[10];
  const float* W2   = (const float*)d_in[11];
  const float* b2   = (const float*)d_in[12];
  const float* ln2g = (const float*)d_in[13];
  const float* ln2b = (const float*)d_in[14];
  const float* hlng = (const float*)d_in[15];
  const float* hlnb = (const float*)d_in[16];
  const float* hW   = (const float*)d_in[17];
  const float* hb   = (const float*)d_in[18];
  float* out = (float*)d_out;

  char* ws = (char*)d_ws;
  size_t off = 0;
  auto alloc = [&](size_t bytes) {
    char* p = ws + off;
    off = (off + bytes + 255) & ~(size_t)255;
    return p;
  };
  unsigned short* Wqkv_b = (unsigned short*)alloc((size_t)NLAYER*3072*1024*2);
  unsigned short* Wo_b   = (unsigned short*)alloc((size_t)NLAYER*1024*1024*2);
  unsigned short* W1_b   = (unsigned short*)alloc((size_t)NLAYER*4096*1024*2);
  unsigned short* W2_b   = (unsigned short*)alloc((size_t)NLAYER*1024*4096*2);
  float*          X      = (float*)alloc((size_t)TOKENS*1024*4);
  unsigned short* Xb     = (unsigned short*)alloc((size_t)TOKENS*1024*2);
  unsigned short* Qb     = (unsigned short*)alloc((size_t)TOKENS*3072*2);  // qkv bf16
  unsigned short* Vtg    = (unsigned short*)alloc((size_t)TOKENS*1024*2);  // V transposed
  float*          Y      = (float*)alloc((size_t)TOKENS*1024*4);
  unsigned short* Ab     = (unsigned short*)alloc((size_t)TOKENS*1024*2);
  unsigned short* Gb     = Qb;  // FF intermediate aliases Qb+Vtg (both dead there)
  float*          cls    = (float*)alloc(8*1024*4);
  float*          mb     = (float*)alloc(TOKENS*4);

  f2b_kernel<<<2048, 256, 0, stream>>>((const float4*)Wqkv, (ushort4*)Wqkv_b, (long)NLAYER*3072*1024/4);
  f2b_kernel<<<2048, 256, 0, stream>>>((const float4*)Wo,   (ushort4*)Wo_b,   (long)NLAYER*1024*1024/4);
  f2b_kernel<<<2048, 256, 0, stream>>>((const float4*)W1,   (ushort4*)W1_b,   (long)NLAYER*4096*1024/4);
  f2b_kernel<<<2048, 256, 0, stream>>>((const float4*)W2,   (ushort4*)W2_b,   (long)NLAYER*1024*4096/4);
  embed_kernel<<<(TOKENS*256)/256, 256, 0, stream>>>(ids, (const float4*)tok, (const float4*)pos,
                                                     (float4*)X, (ushort4*)Xb);
  maskb_kernel<<<TOKENS/256, 256, 0, stream>>>(ids, mb);

  for (int i = 0; i < NLAYER; ++i) {
    gemm128<3><<<dim3(3072/128, TOKENS/128), 256, 0, stream>>>(
        Xb, Wqkv_b + (size_t)i*3072*1024, bqkv + i*3072, nullptr, nullptr, Qb, Vtg, TOKENS, 3072, 1024);
    attn2<<<dim3(SEQ_L/128, NHEAD, SEQ_B), 256, 0, stream>>>(Qb, Vtg, mb, Ab);
    gemm128<0><<<dim3(1024/128, TOKENS/128), 256, 0, stream>>>(
        Ab, Wo_b + (size_t)i*1024*1024, bo + i*1024, X, Y, nullptr, nullptr, TOKENS, 1024, 1024);
    add_ln<<<TOKENS, 256, 0, stream>>>(Y, nullptr, ln1g + i*1024, ln1b + i*1024, X, Xb, 1024L, 1024L);
    gemm128<1><<<dim3(4096/128, TOKENS/128), 256, 0, stream>>>(
        Xb, W1_b + (size_t)i*4096*1024, b1 + i*4096, nullptr, nullptr, Gb, nullptr, TOKENS, 4096, 1024);
    gemm128<0><<<dim3(1024/128, TOKENS/128), 256, 0, stream>>>(
        Gb, W2_b + (size_t)i*1024*4096, b2 + i*1024, X, Y, nullptr, nullptr, TOKENS, 1024, 4096);
    add_ln<<<TOKENS, 256, 0, stream>>>(Y, nullptr, ln2g + i*1024, ln2b + i*1024, X, Xb, 1024L, 1024L);
  }
  add_ln<<<8, 256, 0, stream>>>(X, nullptr, hlng, hlnb, cls, nullptr, (long)SEQ_L*1024, 1024L);
  head_kernel<<<dim3(4, 8), 256, 0, stream>>>(cls, hW, hb, out);
}